// Round 7
// baseline (141.269 us; speedup 1.0000x reference)
//
#include <hip/hip_runtime.h>
#include <hip/hip_bf16.h>

// NT-Xent loss: z1,z2 [4096,256] fp32 -> scalar loss.
// R10: deadlock-proof fused kernel. R9 (512-block fused) died without profile;
// credible causes: (a) 2-blocks/CU residency needs VGPR<=128 which was never
// verified -> barrier deadlock -> timeout; (b) hipMemsetAsync under graph
// capture. Both removed:
//  - grid 256 x 512: 1 block/CU needs only VGPR<=256 (GUARANTEED by
//    __launch_bounds__(512,2)) + 64KB LDS <= 160KB -> all 256 blocks resident
//    by construction, barrier cannot deadlock.
//  - k_zero pre-kernel zeroes barrier words + out (no memsetAsync).
//  - ONE grid barrier (normalize -> gemm). The gemm -> finisher sync is a
//    last-block ticket: each block atomicAdd's a done-counter after its
//    flush; the 256th block runs the finisher alone (~16 logf/thread).
//  - barrier: plain atomicAdd (device-scope, m20) + __threadfence (L2
//    writeback); spin via atomicAdd(ctr,0) — coherent read, never a cached
//    volatile load (cross-XCD L2s not coherent).
// Phase 1 is R8's epilogue-lite gemm on R7's 256-block partition (68us).

#define TWO_N 8192
#define NPAIR 4096
#define DDIM  256
#define NT    64                    // 128-row tiles per dim
#define NBLK  (NT * (NT + 1) / 2)   // 2080 upper-triangle tiles
#define INV_T 2.0f
#define GEMM_GRID 256               // persistent blocks, 1 per CU

typedef __attribute__((ext_vector_type(8))) short bf16x8;
typedef __attribute__((ext_vector_type(4))) float f32x4;

typedef __attribute__((address_space(1))) void gvoid_t;
typedef __attribute__((address_space(3))) void lvoid_t;

__device__ __forceinline__ void gload_lds16(const void* g, void* l) {
    __builtin_amdgcn_global_load_lds((gvoid_t*)g, (lvoid_t*)l, 16, 0, 0);
}

// ---------------- Kernel 0: zero the barrier words + out ----------------
__global__ void k_zero(float* __restrict__ out, unsigned* __restrict__ bar) {
    if (threadIdx.x == 0) { out[0] = 0.0f; bar[0] = 0u; bar[1] = 0u; }
}

// ---------------- Kernel 1: fused normalize + GEMM + finisher ----------------
__global__ __launch_bounds__(512, 2)
void k_fused(const float* __restrict__ z1,
             const float* __restrict__ z2,
             __hip_bfloat16* __restrict__ zn,
             float* __restrict__ e_diag,
             float* __restrict__ pos,
             float* __restrict__ row_sumexp,
             float* __restrict__ out,
             unsigned* __restrict__ bar) {
    __shared__ __align__(128) __hip_bfloat16 Asmem[128 * DDIM];   // 64 KB
    __shared__ unsigned lastFlag;
    __shared__ float ps[8];

    const int tid  = threadIdx.x;
    const int lane = tid & 63;
    const int w    = tid >> 6;

    // ================= phase 0: normalize + pair-dot + zero scratch ========
    {
        if (tid < 32) row_sumexp[blockIdx.x * 32 + tid] = 0.0f;

#pragma unroll
        for (int rep = 0; rep < 2; ++rep) {
            const int i = blockIdx.x * 16 + rep * 8 + w;   // pair index

            float4 a = ((const float4*)(z1 + (size_t)i * DDIM))[lane];
            float4 b = ((const float4*)(z2 + (size_t)i * DDIM))[lane];

            float s1 = a.x * a.x + a.y * a.y + a.z * a.z + a.w * a.w;
            float s2 = b.x * b.x + b.y * b.y + b.z * b.z + b.w * b.w;
            float dd = a.x * b.x + a.y * b.y + a.z * b.z + a.w * b.w;
#pragma unroll
            for (int m = 1; m < 64; m <<= 1) {
                s1 += __shfl_xor(s1, m, 64);
                s2 += __shfl_xor(s2, m, 64);
                dd += __shfl_xor(dd, m, 64);
            }

            float inv1 = 1.0f / fmaxf(sqrtf(s1), 1e-8f);   // matches ref eps
            float inv2 = 1.0f / fmaxf(sqrtf(s2), 1e-8f);

            __hip_bfloat16 q1[4], q2[4];
            q1[0] = __float2bfloat16(a.x * inv1); q1[1] = __float2bfloat16(a.y * inv1);
            q1[2] = __float2bfloat16(a.z * inv1); q1[3] = __float2bfloat16(a.w * inv1);
            q2[0] = __float2bfloat16(b.x * inv2); q2[1] = __float2bfloat16(b.y * inv2);
            q2[2] = __float2bfloat16(b.z * inv2); q2[3] = __float2bfloat16(b.w * inv2);

            float qs1 = 0.0f, qs2 = 0.0f;
#pragma unroll
            for (int j = 0; j < 4; ++j) {
                float f1 = __bfloat162float(q1[j]);
                float f2 = __bfloat162float(q2[j]);
                qs1 += f1 * f1;
                qs2 += f2 * f2;
            }
#pragma unroll
            for (int m = 1; m < 64; m <<= 1) {
                qs1 += __shfl_xor(qs1, m, 64);
                qs2 += __shfl_xor(qs2, m, 64);
            }

            *reinterpret_cast<uint2*>(zn + (size_t)i * DDIM + lane * 4) =
                *reinterpret_cast<uint2*>(q1);
            *reinterpret_cast<uint2*>(zn + (size_t)(i + NPAIR) * DDIM + lane * 4) =
                *reinterpret_cast<uint2*>(q2);

            if (lane == 0) {
                e_diag[i]         = __expf(qs1 * INV_T);   // matches bf16 self-dot
                e_diag[i + NPAIR] = __expf(qs2 * INV_T);
                pos[i]            = dd * inv1 * inv2 * INV_T;
            }
        }
    }

    // ----- grid barrier: zn / e_diag / pos / zeroed sums globally visible ---
    __syncthreads();                        // all waves' stores drained to L2
    if (tid == 0) {
        __threadfence();                    // release: L2 writeback
        atomicAdd(&bar[0], 1u);
        while (atomicAdd(&bar[0], 0u) < (unsigned)GEMM_GRID)   // coherent read
            __builtin_amdgcn_s_sleep(2);
        __threadfence();                    // acquire
    }
    __syncthreads();

    // ================= phase 1: persistent symmetric GEMM (R8 body) ========
    {
        const int wr   = w >> 2;          // 0/1: rows wr*64..+64
        const int wc   = w & 3;           // 0..3: cols wc*32..+32
        const int lr   = lane & 15;
        const int quad = lane >> 4;

        const int t0 = (int)(((long)blockIdx.x * NBLK) >> 8);
        const int t1 = (int)(((long)(blockIdx.x + 1) * NBLK) >> 8);

        int b = t0;
        int rt = (int)(64.5f - sqrtf(64.5f * 64.5f - 2.0f * (float)b));
        if (rt < 0) rt = 0;
        if (rt > NT - 1) rt = NT - 1;
        while (rt > 0 && NT * rt - (rt * (rt - 1)) / 2 > b) --rt;
        while (NT * (rt + 1) - ((rt + 1) * rt) / 2 <= b) ++rt;
        int ct = rt + (b - (NT * rt - (rt * (rt - 1)) / 2));

        int pa[4];
#pragma unroll
        for (int mi = 0; mi < 4; ++mi)
            pa[mi] = (wr * 64 + mi * 16 + lr) * (DDIM * 2) + ((quad ^ (lr & 7)) << 4);

        int cur_rt = -1;
        f32x4 acc[4][2];
        float rs[4][4];
#pragma unroll
        for (int mi = 0; mi < 4; ++mi)
#pragma unroll
            for (int r = 0; r < 4; ++r) rs[mi][r] = 0.0f;
        int  pCol = 0;
        bool pDiag = false, havePrev = false;

        auto epi_accum = [&](float& cs0, float& cs1) {
#pragma unroll
            for (int mi = 0; mi < 4; ++mi)
#pragma unroll
                for (int r = 0; r < 4; ++r) {
                    float e0 = __expf(acc[mi][0][r] * INV_T);
                    float e1 = __expf(acc[mi][1][r] * INV_T);
                    rs[mi][r] += e0 + e1;
                    cs0 += e0;
                    cs1 += e1;
                }
        };
        auto epi_cols = [&](float cs0, float cs1) {
            if (pDiag) { cs0 = 0.0f; cs1 = 0.0f; }
            cs0 += __shfl_xor(cs0, 16, 64); cs0 += __shfl_xor(cs0, 32, 64);
            cs1 += __shfl_xor(cs1, 16, 64); cs1 += __shfl_xor(cs1, 32, 64);
            if (quad == 0) {
                atomicAdd(&row_sumexp[pCol + wc * 32 + lr], cs0);
                atomicAdd(&row_sumexp[pCol + wc * 32 + 16 + lr], cs1);
            }
        };
        auto flush_rows = [&](int rowb) {
#pragma unroll
            for (int mi = 0; mi < 4; ++mi)
#pragma unroll
                for (int r = 0; r < 4; ++r) {
                    float v = rs[mi][r];
                    v += __shfl_xor(v, 1, 64);
                    v += __shfl_xor(v, 2, 64);
                    v += __shfl_xor(v, 4, 64);
                    v += __shfl_xor(v, 8, 64);
                    if (lr == 0)
                        atomicAdd(&row_sumexp[rowb + wr * 64 + mi * 16 + quad * 4 + r], v);
                    rs[mi][r] = 0.0f;
                }
        };

        for (int t = t0; t < t1; ++t) {
            const int  row_base = rt * 128;
            const int  col_base = ct * 128;
            const bool diag     = (rt == ct);
            const bool restage  = (rt != cur_rt);    // block-uniform

            const __hip_bfloat16* gB0 =
                zn + (size_t)(col_base + wc * 32 + lr) * DDIM + quad * 8;
            bf16x8 Bfr[8][2];

            if (restage) {
                if (havePrev) { float c0 = 0.f, c1 = 0.f; epi_accum(c0, c1); epi_cols(c0, c1); }
                if (cur_rt >= 0) flush_rows(cur_rt * 128);
                __syncthreads();   // all waves done reading old A
                const int ck = (tid & 24) | ((tid & 7) ^ ((tid >> 5) & 7));
                const char* gA = (const char*)(zn + (size_t)row_base * DDIM)
                               + (tid >> 5) * (DDIM * 2) + ck * 16;
                char* lA = (char*)Asmem + tid * 16;
#pragma unroll
                for (int j = 0; j < 8; ++j)
                    gload_lds16(gA + (size_t)j * 16 * (DDIM * 2), lA + j * 8192);
#pragma unroll
                for (int ks = 0; ks < 8; ++ks) {
                    const __hip_bfloat16* p0 = gB0 + ks * 32;
                    const __hip_bfloat16* p1 = p0 + 16 * DDIM;
                    asm volatile("global_load_dwordx4 %0, %1, off"
                                 : "=v"(Bfr[ks][0]) : "v"(p0) : "memory");
                    asm volatile("global_load_dwordx4 %0, %1, off"
                                 : "=v"(Bfr[ks][1]) : "v"(p1) : "memory");
                }
                cur_rt = rt;
                asm volatile("s_waitcnt vmcnt(0)" ::: "memory");   // drain A + B
                __syncthreads();                                    // A visible
            } else {
#pragma unroll
                for (int ks = 0; ks < 4; ++ks) {
                    const __hip_bfloat16* p0 = gB0 + ks * 32;
                    const __hip_bfloat16* p1 = p0 + 16 * DDIM;
                    asm volatile("global_load_dwordx4 %0, %1, off"
                                 : "=v"(Bfr[ks][0]) : "v"(p0) : "memory");
                    asm volatile("global_load_dwordx4 %0, %1, off"
                                 : "=v"(Bfr[ks][1]) : "v"(p1) : "memory");
                }
                float c0 = 0.f, c1 = 0.f;
                epi_accum(c0, c1);          // prev-tile exp under B1 latency
#pragma unroll
                for (int ks = 4; ks < 8; ++ks) {
                    const __hip_bfloat16* p0 = gB0 + ks * 32;
                    const __hip_bfloat16* p1 = p0 + 16 * DDIM;
                    asm volatile("global_load_dwordx4 %0, %1, off"
                                 : "=v"(Bfr[ks][0]) : "v"(p0) : "memory");
                    asm volatile("global_load_dwordx4 %0, %1, off"
                                 : "=v"(Bfr[ks][1]) : "v"(p1) : "memory");
                }
                epi_cols(c0, c1);           // exactly 2 VMEM after last B load
                asm volatile("s_waitcnt vmcnt(2)" ::: "memory");   // all B done
            }
            __builtin_amdgcn_sched_barrier(0);   // rule #18: no MFMA hoisting

            pCol = col_base; pDiag = diag; havePrev = true;

#pragma unroll
            for (int mi = 0; mi < 4; ++mi)
#pragma unroll
                for (int ni = 0; ni < 2; ++ni)
                    acc[mi][ni] = (f32x4){0.f, 0.f, 0.f, 0.f};

            bf16x8 afc[4];
#pragma unroll
            for (int mi = 0; mi < 4; ++mi)
                afc[mi] = *(const bf16x8*)((const char*)Asmem + pa[mi]);

#pragma unroll
            for (int kstep = 0; kstep < 8; ++kstep) {
                bf16x8 afn[4];
                if (kstep < 7) {
                    const int kn   = kstep + 1;
                    const int koff = (kn >> 1) << 7;
                    const int kx   = (kn & 1) << 6;
#pragma unroll
                    for (int mi = 0; mi < 4; ++mi)
                        afn[mi] = *(const bf16x8*)((const char*)Asmem + ((pa[mi] ^ kx) + koff));
                }
#pragma unroll
                for (int mi = 0; mi < 4; ++mi)
#pragma unroll
                    for (int ni = 0; ni < 2; ++ni)
                        acc[mi][ni] = __builtin_amdgcn_mfma_f32_16x16x32_bf16(
                            afc[mi], Bfr[kstep][ni], acc[mi][ni], 0, 0, 0);
                if (kstep < 7) {
#pragma unroll
                    for (int mi = 0; mi < 4; ++mi) afc[mi] = afn[mi];
                }
            }

            if (++ct >= NT) { ++rt; ct = rt; }   // advance in the triangle
        }

        { float c0 = 0.f, c1 = 0.f; epi_accum(c0, c1); epi_cols(c0, c1); }
        flush_rows(cur_rt * 128);
    }

    // ----- last-block ticket: the 256th block to finish runs the finisher ---
    __syncthreads();                       // drain this block's atomics
    if (tid == 0) {
        __threadfence();                   // make atomics globally performed
        unsigned prev = atomicAdd(&bar[1], 1u);
        lastFlag = (prev == (unsigned)(GEMM_GRID - 1)) ? 1u : 0u;
    }
    __syncthreads();

    if (lastFlag) {
        // ============= phase 2: finisher, one block, 8 pairs/thread ========
        float t = 0.0f;
        for (int p = tid; p < NPAIR; p += 512) {
            t += logf(row_sumexp[p] - e_diag[p])
               + logf(row_sumexp[p + NPAIR] - e_diag[p + NPAIR])
               - 2.0f * pos[p];
        }
#pragma unroll
        for (int m = 1; m < 64; m <<= 1) t += __shfl_xor(t, m, 64);
        if (lane == 0) ps[w] = t;
        __syncthreads();
        if (tid == 0) {
            float s = 0.0f;
#pragma unroll
            for (int j = 0; j < 8; ++j) s += ps[j];
            out[0] = s * (1.0f / (float)TWO_N);
        }
    }
}

extern "C" void kernel_launch(void* const* d_in, const int* in_sizes, int n_in,
                              void* d_out, int out_size, void* d_ws, size_t ws_size,
                              hipStream_t stream) {
    const float* z1 = (const float*)d_in[0];
    const float* z2 = (const float*)d_in[1];
    float* out = (float*)d_out;

    char* ws = (char*)d_ws;
    __hip_bfloat16* zn  = (__hip_bfloat16*)ws;                       // 4 MB
    float* row_sumexp   = (float*)(ws + (size_t)TWO_N * DDIM * 2);   // 32 KB
    float* e_diag       = row_sumexp + TWO_N;                        // 32 KB
    float* pos          = e_diag + TWO_N;                            // 16 KB
    unsigned* bar       = (unsigned*)(pos + NPAIR);                  // 8 B

    k_zero<<<1, 64, 0, stream>>>(out, bar);
    k_fused<<<GEMM_GRID, 512, 0, stream>>>(z1, z2, zn, e_diag, pos,
                                           row_sumexp, out, bar);
}

// Round 8
// 132.867 us; speedup vs baseline: 1.0632x; 1.0632x over previous
//
#include <hip/hip_runtime.h>
#include <hip/hip_bf16.h>

// NT-Xent loss: z1,z2 [4096,256] fp32 -> scalar loss.
// R11: full-matrix row-streamed GEMM; fusion reverted. R10 proved launch-gap
// overhead ~0/launch (total-kernels ~= 50us fixed at 2,3,4 dispatches) and
// fusion cost +15us. R3-R8 showed per-tile cost ~11k cy invariant: the
// triangle machinery (per-tile col shuffles+atomics, restage barriers,
// vmcnt-vs-atomic ordering) IS the overhead. FLOPs are 91% idle -> spend
// them: compute the FULL 8192x8192 sim matrix, row-panel-streamed:
//  - grid 512 = 64 row-panels x 8 ct-chunks; block stages its A panel ONCE
//    (zero restages, zero in-loop __syncthreads);
//  - per tile: issue 16 opaque B loads -> prev-tile exp under the latency ->
//    vmcnt(0) -> pure LDS+MFMA k-loop. No atomics in the loop at all;
//  - row sums accumulate in regs across the block's 8 tiles, ONE flush;
//  - bid&7 = chunk -> each XCD owns a fixed 1024-col B strip (512 KB,
//    L2-resident); zn (4 MB) fits every XCD L2.
// Kept: XOR-swizzled A tile + verified pa/kx/koff walk, opaque asm B loads,
// sched_barrier after waitcnt (rule #18), pair-dot in k_normalize.

#define TWO_N 8192
#define NPAIR 4096
#define DDIM  256
#define NT    64                    // 128-row tiles per dim
#define INV_T 2.0f

typedef __attribute__((ext_vector_type(8))) short bf16x8;
typedef __attribute__((ext_vector_type(4))) float f32x4;

typedef __attribute__((address_space(1))) void gvoid_t;
typedef __attribute__((address_space(3))) void lvoid_t;

__device__ __forceinline__ void gload_lds16(const void* g, void* l) {
    __builtin_amdgcn_global_load_lds((gvoid_t*)g, (lvoid_t*)l, 16, 0, 0);
}

// ---------------- Kernel 1: normalize + quantize + pair-dot + zero scratch --
// grid 1024 x 256: one wave per PAIR i (handles rows i and i+4096).
__global__ void k_normalize(const float* __restrict__ z1,
                            const float* __restrict__ z2,
                            __hip_bfloat16* __restrict__ zn,
                            float* __restrict__ e_diag,
                            float* __restrict__ pos,
                            float* __restrict__ row_sumexp,
                            float* __restrict__ out) {
    if (threadIdx.x < 8) row_sumexp[blockIdx.x * 8 + threadIdx.x] = 0.0f;
    if (blockIdx.x == 0 && threadIdx.x == 0) out[0] = 0.0f;

    const int w    = threadIdx.x >> 6;
    const int lane = threadIdx.x & 63;
    const int i    = blockIdx.x * 4 + w;

    float4 a = ((const float4*)(z1 + (size_t)i * DDIM))[lane];
    float4 b = ((const float4*)(z2 + (size_t)i * DDIM))[lane];

    float s1 = a.x * a.x + a.y * a.y + a.z * a.z + a.w * a.w;
    float s2 = b.x * b.x + b.y * b.y + b.z * b.z + b.w * b.w;
    float dd = a.x * b.x + a.y * b.y + a.z * b.z + a.w * b.w;
#pragma unroll
    for (int m = 1; m < 64; m <<= 1) {
        s1 += __shfl_xor(s1, m, 64);
        s2 += __shfl_xor(s2, m, 64);
        dd += __shfl_xor(dd, m, 64);
    }

    float inv1 = 1.0f / fmaxf(sqrtf(s1), 1e-8f);   // matches reference eps
    float inv2 = 1.0f / fmaxf(sqrtf(s2), 1e-8f);

    __hip_bfloat16 q1[4], q2[4];
    q1[0] = __float2bfloat16(a.x * inv1); q1[1] = __float2bfloat16(a.y * inv1);
    q1[2] = __float2bfloat16(a.z * inv1); q1[3] = __float2bfloat16(a.w * inv1);
    q2[0] = __float2bfloat16(b.x * inv2); q2[1] = __float2bfloat16(b.y * inv2);
    q2[2] = __float2bfloat16(b.z * inv2); q2[3] = __float2bfloat16(b.w * inv2);

    float qs1 = 0.0f, qs2 = 0.0f;
#pragma unroll
    for (int j = 0; j < 4; ++j) {
        float f1 = __bfloat162float(q1[j]);
        float f2 = __bfloat162float(q2[j]);
        qs1 += f1 * f1;
        qs2 += f2 * f2;
    }
#pragma unroll
    for (int m = 1; m < 64; m <<= 1) {
        qs1 += __shfl_xor(qs1, m, 64);
        qs2 += __shfl_xor(qs2, m, 64);
    }

    *reinterpret_cast<uint2*>(zn + (size_t)i * DDIM + lane * 4) =
        *reinterpret_cast<uint2*>(q1);
    *reinterpret_cast<uint2*>(zn + (size_t)(i + NPAIR) * DDIM + lane * 4) =
        *reinterpret_cast<uint2*>(q2);

    if (lane == 0) {
        e_diag[i]         = __expf(qs1 * INV_T);   // matches GEMM's bf16 self-dot
        e_diag[i + NPAIR] = __expf(qs2 * INV_T);
        pos[i]            = dd * inv1 * inv2 * INV_T;  // positive-pair term, fp32
    }
}

// ---------------- Kernel 2: full-matrix row-streamed MFMA GEMM + row sums ---
// 512 blocks x 512 threads (8 waves, 2x4 over a 128x128 tile).
// block: panel = bid>>3 (rows panel*128..+127), chunk = bid&7
// (tiles ct = chunk*8 .. chunk*8+7). A panel staged once; 8 tile iterations;
// row sums accumulated in regs, flushed once.
__global__ __launch_bounds__(512, 2)
void k_gemm_rows(const __hip_bfloat16* __restrict__ zn,
                 float* __restrict__ row_sumexp) {
    __shared__ __align__(128) __hip_bfloat16 Asmem[128 * DDIM];   // 64 KB

    const int tid  = threadIdx.x;
    const int lane = tid & 63;
    const int w    = tid >> 6;
    const int wr   = w >> 2;          // 0/1: rows wr*64..+64
    const int wc   = w & 3;           // 0..3: cols wc*32..+32
    const int lr   = lane & 15;
    const int quad = lane >> 4;

    const int panel    = blockIdx.x >> 3;       // 0..63
    const int chunk    = blockIdx.x & 7;        // 0..7 (== XCD id mod 8)
    const int row_base = panel * 128;

    // --- stage A panel ONCE: 512 thr x 8 rounds x 16B, XOR-swizzled.
    //     slot s = j*512+tid -> row = j*16+(tid>>5), chunk slot c'=tid&31,
    //     source chunk ck = (c'&24)|((c'&7)^(row&7)). ---
    {
        const int ck = (tid & 24) | ((tid & 7) ^ ((tid >> 5) & 7));
        const char* gA = (const char*)(zn + (size_t)row_base * DDIM)
                       + (tid >> 5) * (DDIM * 2) + ck * 16;
        char* lA = (char*)Asmem + tid * 16;
#pragma unroll
        for (int j = 0; j < 8; ++j)
            gload_lds16(gA + (size_t)j * 16 * (DDIM * 2), lA + j * 8192);
    }

    // --- A fragment LDS byte offsets (swizzled; verified R3-R8) ---
    int pa[4];
#pragma unroll
    for (int mi = 0; mi < 4; ++mi)
        pa[mi] = (wr * 64 + mi * 16 + lr) * (DDIM * 2) + ((quad ^ (lr & 7)) << 4);

    f32x4 acc[4][2];
    float rs[4][4];
#pragma unroll
    for (int mi = 0; mi < 4; ++mi)
#pragma unroll
        for (int r = 0; r < 4; ++r) rs[mi][r] = 0.0f;

    // exp + accumulate the just-finished tile's acc into rs. Pure VALU.
    auto epi_accum = [&]() {
#pragma unroll
        for (int mi = 0; mi < 4; ++mi)
#pragma unroll
            for (int r = 0; r < 4; ++r) {
                rs[mi][r] += __expf(acc[mi][0][r] * INV_T)
                           + __expf(acc[mi][1][r] * INV_T);
            }
    };

#pragma unroll 1
    for (int tt = 0; tt < 8; ++tt) {
        const int col_base = (chunk * 8 + tt) * 128;
        const __hip_bfloat16* gB0 =
            zn + (size_t)(col_base + wc * 32 + lr) * DDIM + quad * 8;

        // issue this tile's FULL B panel: 16 opaque 16B loads/lane
        bf16x8 Bfr[8][2];
#pragma unroll
        for (int ks = 0; ks < 8; ++ks) {
            const __hip_bfloat16* p0 = gB0 + ks * 32;
            const __hip_bfloat16* p1 = p0 + 16 * DDIM;
            asm volatile("global_load_dwordx4 %0, %1, off"
                         : "=v"(Bfr[ks][0]) : "v"(p0) : "memory");
            asm volatile("global_load_dwordx4 %0, %1, off"
                         : "=v"(Bfr[ks][1]) : "v"(p1) : "memory");
        }

        if (tt == 0) {
            // drain A staging + B(0); then make A visible to all waves
            asm volatile("s_waitcnt vmcnt(0)" ::: "memory");
            __syncthreads();                   // the ONLY barrier in the kernel
        } else {
            epi_accum();                       // prev tile's exp under B latency
            asm volatile("s_waitcnt vmcnt(0)" ::: "memory");
        }
        __builtin_amdgcn_sched_barrier(0);     // rule #18: no MFMA hoisting

#pragma unroll
        for (int mi = 0; mi < 4; ++mi)
#pragma unroll
            for (int ni = 0; ni < 2; ++ni)
                acc[mi][ni] = (f32x4){0.f, 0.f, 0.f, 0.f};

        bf16x8 afc[4];
#pragma unroll
        for (int mi = 0; mi < 4; ++mi)
            afc[mi] = *(const bf16x8*)((const char*)Asmem + pa[mi]);

        // --- pure LDS+register k-loop: zero global ops, zero barriers ---
#pragma unroll
        for (int kstep = 0; kstep < 8; ++kstep) {
            bf16x8 afn[4];
            if (kstep < 7) {
                const int kn   = kstep + 1;
                const int koff = (kn >> 1) << 7;
                const int kx   = (kn & 1) << 6;
#pragma unroll
                for (int mi = 0; mi < 4; ++mi)
                    afn[mi] = *(const bf16x8*)((const char*)Asmem + ((pa[mi] ^ kx) + koff));
            }
#pragma unroll
            for (int mi = 0; mi < 4; ++mi)
#pragma unroll
                for (int ni = 0; ni < 2; ++ni)
                    acc[mi][ni] = __builtin_amdgcn_mfma_f32_16x16x32_bf16(
                        afc[mi], Bfr[kstep][ni], acc[mi][ni], 0, 0, 0);
            if (kstep < 7) {
#pragma unroll
                for (int mi = 0; mi < 4; ++mi) afc[mi] = afn[mi];
            }
        }
    }

    epi_accum();   // last tile

    // --- single row flush: the only atomics in the kernel.
    //     C/D layout (verified): col = lane&15, row = quad*4 + reg. ---
#pragma unroll
    for (int mi = 0; mi < 4; ++mi) {
#pragma unroll
        for (int r = 0; r < 4; ++r) {
            float v = rs[mi][r];
            v += __shfl_xor(v, 1, 64);
            v += __shfl_xor(v, 2, 64);
            v += __shfl_xor(v, 4, 64);
            v += __shfl_xor(v, 8, 64);
            if (lr == 0)
                atomicAdd(&row_sumexp[row_base + wr * 64 + mi * 16 + quad * 4 + r], v);
        }
    }
}

// ---------------- Kernel 3: tiny finisher ----------------
// grid 16 x 256: one thread per pair index.
__global__ void k_final(const float* __restrict__ row_sumexp,
                        const float* __restrict__ e_diag,
                        const float* __restrict__ pos,
                        float* __restrict__ out) {
    const int i    = blockIdx.x * 256 + threadIdx.x;   // 0..4095
    const int w    = threadIdx.x >> 6;
    const int lane = threadIdx.x & 63;

    float t = logf(row_sumexp[i] - e_diag[i])
            + logf(row_sumexp[i + NPAIR] - e_diag[i + NPAIR])
            - 2.0f * pos[i];
#pragma unroll
    for (int m = 1; m < 64; m <<= 1) t += __shfl_xor(t, m, 64);

    __shared__ float ps[4];
    if (lane == 0) ps[w] = t;
    __syncthreads();
    if (threadIdx.x == 0) {
        float s = (ps[0] + ps[1] + ps[2] + ps[3]) * (1.0f / (float)TWO_N);
        atomicAdd(out, s);
    }
}

extern "C" void kernel_launch(void* const* d_in, const int* in_sizes, int n_in,
                              void* d_out, int out_size, void* d_ws, size_t ws_size,
                              hipStream_t stream) {
    const float* z1 = (const float*)d_in[0];
    const float* z2 = (const float*)d_in[1];
    float* out = (float*)d_out;

    char* ws = (char*)d_ws;
    __hip_bfloat16* zn  = (__hip_bfloat16*)ws;                       // 4 MB
    float* row_sumexp   = (float*)(ws + (size_t)TWO_N * DDIM * 2);   // 32 KB
    float* e_diag       = row_sumexp + TWO_N;                        // 32 KB
    float* pos          = e_diag + TWO_N;                            // 16 KB

    k_normalize<<<NPAIR / 4, 256, 0, stream>>>(z1, z2, zn, e_diag, pos,
                                               row_sumexp, out);
    k_gemm_rows<<<NT * 8, 512, 0, stream>>>(zn, row_sumexp);
    k_final<<<NPAIR / 256, 256, 0, stream>>>(row_sumexp, e_diag, pos, out);
}